// Round 4
// baseline (48.636 us; speedup 1.0000x reference)
//
#include <hip/hip_runtime.h>

// Depthwise causal conv1d: B=8, T=4096, C=1024, K=4, dilation=1.
// y[b,t,c] = sum_{k=0..3} w[c,k] * x[b, t-3+k, c]   (x zero-padded on the left)
//
// x layout (B,T,C) fp32: channels contiguous -> float4 per thread, 256 threads
// cover C=1024. Each block owns one (b, 16-wide t-tile).
//
// Three strictly-fenced phases (sched_barrier(0) keeps hipcc from re-fusing
// loads with uses, which round 3 proved it does: VGPR stayed 32):
//   1. issue all 19 loads (3 halo + 16 rows)  -> 19 KB in flight per wave
//   2. compute outputs in REVERSE, in place   -> no extra registers
//   3. 16 nontemporal stores                  -> loads never wait on stores
//      in the in-order vmcnt queue.
// NT stores keep y out of L2/L3 so the Infinity Cache holds x.

#define T_TILE 16

typedef float f32x4 __attribute__((ext_vector_type(4)));

__global__ __launch_bounds__(256, 4) void DepthwiseCausalConv1d_57870389346354_kernel(
    const float4* __restrict__ x,   // (B*T*C/4) float4
    const float4* __restrict__ w,   // (C) float4 : channel c's 4 taps
    float4* __restrict__ y,
    int T, int C4)
{
    const int tiles_per_b = T / T_TILE;
    const int tile = blockIdx.x;
    const int b  = tile / tiles_per_b;
    const int t0 = (tile % tiles_per_b) * T_TILE;
    const int c4 = threadIdx.x;              // 0..255 -> channels 4*c4..4*c4+3

    // Taps for the 4 channels this thread owns. weight is (C,4) fp32: the
    // float4 at index c holds channel c's taps k=0..3.
    const float4 w0 = w[4 * c4 + 0];
    const float4 w1 = w[4 * c4 + 1];
    const float4 w2 = w[4 * c4 + 2];
    const float4 w3 = w[4 * c4 + 3];

    const float4* xb = x + (size_t)b * T * C4 + c4;
    float4*       yb = y + (size_t)b * T * C4 + c4;

    const float4 zero = make_float4(0.f, 0.f, 0.f, 0.f);

    // ---- phase 1: ALL loads. v[0..2] = halo rows t0-3..t0-1, v[3+u] = row u.
    float4 v[T_TILE + 3];
    v[0] = (t0 >= 3) ? xb[(size_t)(t0 - 3) * C4] : zero;
    v[1] = (t0 >= 2) ? xb[(size_t)(t0 - 2) * C4] : zero;
    v[2] = (t0 >= 1) ? xb[(size_t)(t0 - 1) * C4] : zero;
#pragma unroll
    for (int u = 0; u < T_TILE; ++u)
        v[3 + u] = xb[(size_t)(t0 + u) * C4];

    __builtin_amdgcn_sched_barrier(0);   // loads stay above; nothing sinks in

    // ---- phase 2: compute in reverse, in place. Output u reads
    // v[u..u+3] and overwrites v[u+3]; later iterations (u-1, u-2, ...)
    // only read v[<u+3], so in-place is safe. All indices compile-time.
#pragma unroll
    for (int u = T_TILE - 1; u >= 0; --u) {
        const float4 a = v[u], bb = v[u + 1], cc = v[u + 2], dd = v[u + 3];
        float4 out;
        out.x = w0.x * a.x + w0.y * bb.x + w0.z * cc.x + w0.w * dd.x;
        out.y = w1.x * a.y + w1.y * bb.y + w1.z * cc.y + w1.w * dd.y;
        out.z = w2.x * a.z + w2.y * bb.z + w2.z * cc.z + w2.w * dd.z;
        out.w = w3.x * a.w + w3.y * bb.w + w3.z * cc.w + w3.w * dd.w;
        v[u + 3] = out;
    }

    __builtin_amdgcn_sched_barrier(0);   // stores stay below the compute

    // ---- phase 3: streaming stores (write-once data; keep out of caches)
#pragma unroll
    for (int u = 0; u < T_TILE; ++u)
        __builtin_nontemporal_store(*(const f32x4*)&v[3 + u],
                                    (f32x4*)&yb[(size_t)(t0 + u) * C4]);
}

extern "C" void kernel_launch(void* const* d_in, const int* in_sizes, int n_in,
                              void* d_out, int out_size, void* d_ws, size_t ws_size,
                              hipStream_t stream)
{
    (void)in_sizes; (void)n_in; (void)out_size; (void)d_ws; (void)ws_size;
    constexpr int B = 8, T = 4096, C = 1024;

    const float4* x = (const float4*)d_in[0];
    const float4* w = (const float4*)d_in[1];
    float4*       y = (float4*)d_out;

    dim3 block(C / 4);                       // 256 threads = 4 waves
    dim3 grid(B * (T / T_TILE));             // 8 * 256 = 2048 blocks

    DepthwiseCausalConv1d_57870389346354_kernel<<<grid, block, 0, stream>>>(
        x, w, y, T, C / 4);
}

// Round 6
// 47.144 us; speedup vs baseline: 1.0316x; 1.0316x over previous
//
#include <hip/hip_runtime.h>

// Depthwise causal conv1d: B=8, T=4096, C=1024, K=4, dilation=1.
// y[b,t,c] = sum_{k=0..3} w[c,k] * x[b, t-3+k, c]   (x zero-padded on the left)
//
// x layout (B,T,C) fp32: channels contiguous -> float4 per thread, 256 threads
// cover C=1024. Each block owns one (b, 16-wide t-tile).
//
// MLP is FORCED via inline-asm loads: rounds 3/4 showed the compiler sinks
// C-level loads back to their uses (VGPR stayed 32/52), leaving only ~2 KB
// in flight per CU vs the ~5-6 KB needed to cover HBM latency. 19 volatile
// asm global_load_dwordx4 -> results pinned live in VGPRs -> 304 B in
// flight per wave. One s_waitcnt vmcnt(0) + sched_barrier(0) (rule #18
// fence) before compute. Stores are builtin-nontemporal (proven correct;
// the sc0/sc1/nt asm store of round 5 broke cache coherence vs the
// harness's poisoned output lines).

#define T_TILE 16

typedef float f32x4 __attribute__((ext_vector_type(4)));

__device__ __forceinline__ f32x4 load_vec(const float4* p) {
    f32x4 r;
    asm volatile("global_load_dwordx4 %0, %1, off" : "=v"(r) : "v"(p));
    return r;
}

__global__ __launch_bounds__(256, 4) void DepthwiseCausalConv1d_57870389346354_kernel(
    const float4* __restrict__ x,   // (B*T*C/4) float4
    const float4* __restrict__ w,   // (C) float4 : channel c's 4 taps
    float4* __restrict__ y,
    int T, int C4)
{
    const int tiles_per_b = T / T_TILE;
    const int tile = blockIdx.x;
    const int b  = tile / tiles_per_b;
    const int t0 = (tile % tiles_per_b) * T_TILE;
    const int c4 = threadIdx.x;              // 0..255 -> channels 4*c4..4*c4+3

    // Taps for the 4 channels this thread owns (weight is (C,4) fp32).
    const float4 w0 = w[4 * c4 + 0];
    const float4 w1 = w[4 * c4 + 1];
    const float4 w2 = w[4 * c4 + 2];
    const float4 w3 = w[4 * c4 + 3];

    const float4* xb = x + (size_t)b * T * C4 + c4;
    float4*       yb = y + (size_t)b * T * C4 + c4;

    // ---- phase 1: issue ALL 19 loads via volatile asm (pinned live). ----
    // t0 is a multiple of 16, so either t0 == 0 (all 3 halo rows are zero)
    // or t0 >= 16 (all halo loads valid). For t0 == 0 we load row 0 (safe
    // address) and overwrite with zeros after the wait.
    f32x4 v[T_TILE + 3];
    v[0] = load_vec(xb + (size_t)((t0 >= 3) ? t0 - 3 : 0) * C4);
    v[1] = load_vec(xb + (size_t)((t0 >= 2) ? t0 - 2 : 0) * C4);
    v[2] = load_vec(xb + (size_t)((t0 >= 1) ? t0 - 1 : 0) * C4);
#pragma unroll
    for (int u = 0; u < T_TILE; ++u)
        v[3 + u] = load_vec(xb + (size_t)(t0 + u) * C4);

    // ---- the fence: drain loads, and keep ALL dependent VALU below it ----
    asm volatile("s_waitcnt vmcnt(0)" ::: "memory");
    __builtin_amdgcn_sched_barrier(0);

    if (t0 == 0) {
        v[0] = (f32x4)0.f;
        v[1] = (f32x4)0.f;
        v[2] = (f32x4)0.f;
    }

    // ---- phase 2: compute in reverse, in place. Output u reads v[u..u+3]
    // and overwrites v[u+3]; later (smaller-u) outputs only read v[<u+3].
    // All indices compile-time (rule #20).
#pragma unroll
    for (int u = T_TILE - 1; u >= 0; --u) {
        const f32x4 a = v[u], bb = v[u + 1], cc = v[u + 2], dd = v[u + 3];
        f32x4 out;
        out.x = w0.x * a.x + w0.y * bb.x + w0.z * cc.x + w0.w * dd.x;
        out.y = w1.x * a.y + w1.y * bb.y + w1.z * cc.y + w1.w * dd.y;
        out.z = w2.x * a.z + w2.y * bb.z + w2.z * cc.z + w2.w * dd.z;
        out.w = w3.x * a.w + w3.y * bb.w + w3.z * cc.w + w3.w * dd.w;
        v[u + 3] = out;
    }

    // ---- phase 3: streaming stores (write-once; keep L2/L3 retention low
    // so the Infinity Cache holds x across graph replays). Builtin nt store
    // stays cache-coherent, unlike the sc0/sc1 asm variant.
#pragma unroll
    for (int u = 0; u < T_TILE; ++u)
        __builtin_nontemporal_store(v[3 + u],
                                    (f32x4*)&yb[(size_t)(t0 + u) * C4]);
}

extern "C" void kernel_launch(void* const* d_in, const int* in_sizes, int n_in,
                              void* d_out, int out_size, void* d_ws, size_t ws_size,
                              hipStream_t stream)
{
    (void)in_sizes; (void)n_in; (void)out_size; (void)d_ws; (void)ws_size;
    constexpr int B = 8, T = 4096, C = 1024;

    const float4* x = (const float4*)d_in[0];
    const float4* w = (const float4*)d_in[1];
    float4*       y = (float4*)d_out;

    dim3 block(C / 4);                       // 256 threads = 4 waves
    dim3 grid(B * (T / T_TILE));             // 8 * 256 = 2048 blocks

    DepthwiseCausalConv1d_57870389346354_kernel<<<grid, block, 0, stream>>>(
        x, w, y, T, C / 4);
}

// Round 7
// 45.887 us; speedup vs baseline: 1.0599x; 1.0274x over previous
//
#include <hip/hip_runtime.h>

// Depthwise causal conv1d: B=8, T=4096, C=1024, K=4, dilation=1.
// y[b,t,c] = sum_{k=0..3} w[c,k] * x[b, t-3+k, c]   (x zero-padded on the left)
//
// Round-7 structure: software-pipelined tiles with COUNTED vmcnt waits.
// Diagnosis from rounds 2-6: every variant did {loads -> vmcnt(0) -> stores}
// per wave, in lockstep across all waves -> the HBM bus alternates between a
// global read burst and a global write burst (t_read + t_write ~ 42us,
// matching the measured 47us). This version keeps the next tile's loads in
// flight while the current tile computes+stores, so reads and writes overlap.
//
// Each block: one (b, 32-row span) = 4 tiles x 8 rows. 1-ahead pipeline:
//   prologue: load halo(3) + T0(8)            -> 11 outstanding
//   k=0: issue T1(8); vmcnt(8)  [T0 ready]; compute+store T0   (8 st)
//   k=1: issue T2(8); vmcnt(16) [T1 ready]; compute+store T1
//   k=2: issue T3(8); vmcnt(16) [T2 ready]; compute+store T2
//   k=3:              vmcnt(8)  [T3 ready]; compute+store T3
// vmcnt retires in issue order, so "<= N outstanding" == "tile k's loads
// done" with N = (ops issued after tile k's loads).
// Sliding window carries across tiles in registers (no halo reloads).
// Stores are builtin-nontemporal (round 2: write amplification 260->139 MB;
// round 5 proved sc0/sc1 MALL-bypass is NOT coherent with the harness).

#define ROWS 8
#define TILES 4
#define T_SPAN (ROWS * TILES)   // 32

typedef float f32x4 __attribute__((ext_vector_type(4)));

__device__ __forceinline__ f32x4 load_vec(const float4* p) {
    f32x4 r;
    asm volatile("global_load_dwordx4 %0, %1, off" : "=v"(r) : "v"(p));
    return r;
}

__global__ __launch_bounds__(256) void DepthwiseCausalConv1d_57870389346354_kernel(
    const float4* __restrict__ x,   // (B*T*C/4) float4
    const float4* __restrict__ w,   // (C) float4 : channel c's 4 taps
    float4* __restrict__ y,
    int T, int C4)
{
    const int spans_per_b = T / T_SPAN;            // 128
    const int b  = blockIdx.x / spans_per_b;
    const int t0 = (blockIdx.x % spans_per_b) * T_SPAN;
    const int c4 = threadIdx.x;                    // 0..255 -> channels 4c..4c+3

    const float4 w0 = w[4 * c4 + 0];
    const float4 w1 = w[4 * c4 + 1];
    const float4 w2 = w[4 * c4 + 2];
    const float4 w3 = w[4 * c4 + 3];

    const float4* xb = x + (size_t)b * T * C4 + c4;
    float4*       yb = y + (size_t)b * T * C4 + c4;

    // ---- prologue: halo (or safe row-0 loads, zeroed after first wait) + T0
    f32x4 wm3 = load_vec(xb + (size_t)((t0 >= 3) ? t0 - 3 : 0) * C4);
    f32x4 wm2 = load_vec(xb + (size_t)((t0 >= 2) ? t0 - 2 : 0) * C4);
    f32x4 wm1 = load_vec(xb + (size_t)((t0 >= 1) ? t0 - 1 : 0) * C4);

    f32x4 tile[2][ROWS];
#pragma unroll
    for (int u = 0; u < ROWS; ++u)
        tile[0][u] = load_vec(xb + (size_t)(t0 + u) * C4);

#pragma unroll
    for (int k = 0; k < TILES; ++k) {
        // issue next tile's loads BEFORE waiting on the current tile
        if (k + 1 < TILES) {
#pragma unroll
            for (int u = 0; u < ROWS; ++u)
                tile[(k + 1) & 1][u] =
                    load_vec(xb + (size_t)(t0 + (k + 1) * ROWS + u) * C4);
        }

        // counted wait: exactly "ops issued after tile k's loads" may remain
        if (k == 0)              asm volatile("s_waitcnt vmcnt(8)"  ::: "memory");
        else if (k == TILES - 1) asm volatile("s_waitcnt vmcnt(8)"  ::: "memory");
        else                     asm volatile("s_waitcnt vmcnt(16)" ::: "memory");
        __builtin_amdgcn_sched_barrier(0);   // rule #18: no VALU hoists above

        if (k == 0 && t0 == 0) {             // left edge: halo is zeros
            wm3 = (f32x4)0.f; wm2 = (f32x4)0.f; wm1 = (f32x4)0.f;
        }

#pragma unroll
        for (int u = 0; u < ROWS; ++u) {
            const f32x4 cur = tile[k & 1][u];
            f32x4 out;
            out.x = w0.x * wm3.x + w0.y * wm2.x + w0.z * wm1.x + w0.w * cur.x;
            out.y = w1.x * wm3.y + w1.y * wm2.y + w1.z * wm1.y + w1.w * cur.y;
            out.z = w2.x * wm3.z + w2.y * wm2.z + w2.z * wm1.z + w2.w * cur.z;
            out.w = w3.x * wm3.w + w3.y * wm2.w + w3.z * wm1.w + w3.w * cur.w;
            __builtin_nontemporal_store(out,
                (f32x4*)&yb[(size_t)(t0 + k * ROWS + u) * C4]);
            wm3 = wm2; wm2 = wm1; wm1 = cur;
        }
    }
}

extern "C" void kernel_launch(void* const* d_in, const int* in_sizes, int n_in,
                              void* d_out, int out_size, void* d_ws, size_t ws_size,
                              hipStream_t stream)
{
    (void)in_sizes; (void)n_in; (void)out_size; (void)d_ws; (void)ws_size;
    constexpr int B = 8, T = 4096, C = 1024;

    const float4* x = (const float4*)d_in[0];
    const float4* w = (const float4*)d_in[1];
    float4*       y = (float4*)d_out;

    dim3 block(C / 4);                        // 256 threads = 4 waves
    dim3 grid(B * (T / T_SPAN));              // 8 * 128 = 1024 blocks

    DepthwiseCausalConv1d_57870389346354_kernel<<<grid, block, 0, stream>>>(
        x, w, y, T, C / 4);
}

// Round 9
// 45.512 us; speedup vs baseline: 1.0686x; 1.0082x over previous
//
#include <hip/hip_runtime.h>

// Depthwise causal conv1d: B=8, T=4096, C=1024, K=4, dilation=1.
// y[b,t,c] = sum_{k=0..3} w[c,k] * x[b, t-3+k, c]   (x zero-padded on the left)
//
// Round-9: round-7's proven pipelined structure (counted vmcnt waits,
// builtin nontemporal stores — BOTH asm cache-policy variants sc0/sc1/nt
// failed harness coherence in rounds 5 & 8), with T_SPAN doubled 32 -> 64
// to halve the halo re-read overhead (9.4% -> 4.7% of read traffic).
//
// Roofline accounting: logical traffic = 134 MB reads + 131 MB writes +
// halo. At T_SPAN=32 round 7 moved ~277 MB in 45.9 us = 6.0 TB/s = ~96% of
// the 6.3 TB/s measured copy ceiling. This is the last ~1 us of headroom.
//
// Pipeline per block (8 tiles x 8 rows, 1-ahead):
//   prologue: load halo(3) + T0(8)
//   k:   issue T{k+1}(8); vmcnt(N) [tile k's loads done]; compute+store k
//   N = 8 for k=0 (only T1's loads behind), 16 mid-loop (next tile's 8
//   loads + previous tile's 8 stores), 8 for the last tile (stores only).
//   vmcnt retires in issue order, so these bounds are exact.
// Sliding window (3 rows) carries across tiles in registers.

#define ROWS 8
#define TILES 8
#define T_SPAN (ROWS * TILES)   // 64

typedef float f32x4 __attribute__((ext_vector_type(4)));

__device__ __forceinline__ f32x4 load_vec(const float4* p) {
    f32x4 r;
    asm volatile("global_load_dwordx4 %0, %1, off" : "=v"(r) : "v"(p));
    return r;
}

__global__ __launch_bounds__(256) void DepthwiseCausalConv1d_57870389346354_kernel(
    const float4* __restrict__ x,   // (B*T*C/4) float4
    const float4* __restrict__ w,   // (C) float4 : channel c's 4 taps
    float4* __restrict__ y,
    int T, int C4)
{
    const int spans_per_b = T / T_SPAN;            // 64
    const int b  = blockIdx.x / spans_per_b;
    const int t0 = (blockIdx.x % spans_per_b) * T_SPAN;
    const int c4 = threadIdx.x;                    // 0..255 -> channels 4c..4c+3

    const float4 w0 = w[4 * c4 + 0];
    const float4 w1 = w[4 * c4 + 1];
    const float4 w2 = w[4 * c4 + 2];
    const float4 w3 = w[4 * c4 + 3];

    const float4* xb = x + (size_t)b * T * C4 + c4;
    float4*       yb = y + (size_t)b * T * C4 + c4;

    // ---- prologue: halo (or safe row-0 loads, zeroed after first wait) + T0
    f32x4 wm3 = load_vec(xb + (size_t)((t0 >= 3) ? t0 - 3 : 0) * C4);
    f32x4 wm2 = load_vec(xb + (size_t)((t0 >= 2) ? t0 - 2 : 0) * C4);
    f32x4 wm1 = load_vec(xb + (size_t)((t0 >= 1) ? t0 - 1 : 0) * C4);

    f32x4 tile[2][ROWS];
#pragma unroll
    for (int u = 0; u < ROWS; ++u)
        tile[0][u] = load_vec(xb + (size_t)(t0 + u) * C4);

#pragma unroll
    for (int k = 0; k < TILES; ++k) {
        // issue next tile's loads BEFORE waiting on the current tile
        if (k + 1 < TILES) {
#pragma unroll
            for (int u = 0; u < ROWS; ++u)
                tile[(k + 1) & 1][u] =
                    load_vec(xb + (size_t)(t0 + (k + 1) * ROWS + u) * C4);
        }

        // counted wait: exactly "ops issued after tile k's loads" may remain
        if (k == 0)              asm volatile("s_waitcnt vmcnt(8)"  ::: "memory");
        else if (k == TILES - 1) asm volatile("s_waitcnt vmcnt(8)"  ::: "memory");
        else                     asm volatile("s_waitcnt vmcnt(16)" ::: "memory");
        __builtin_amdgcn_sched_barrier(0);   // rule #18: no VALU hoists above

        if (k == 0 && t0 == 0) {             // left edge: halo is zeros
            wm3 = (f32x4)0.f; wm2 = (f32x4)0.f; wm1 = (f32x4)0.f;
        }

#pragma unroll
        for (int u = 0; u < ROWS; ++u) {
            const f32x4 cur = tile[k & 1][u];
            f32x4 out;
            out.x = w0.x * wm3.x + w0.y * wm2.x + w0.z * wm1.x + w0.w * cur.x;
            out.y = w1.x * wm3.y + w1.y * wm2.y + w1.z * wm1.y + w1.w * cur.y;
            out.z = w2.x * wm3.z + w2.y * wm2.z + w2.z * wm1.z + w2.w * cur.z;
            out.w = w3.x * wm3.w + w3.y * wm2.w + w3.z * wm1.w + w3.w * cur.w;
            __builtin_nontemporal_store(out,
                (f32x4*)&yb[(size_t)(t0 + k * ROWS + u) * C4]);
            wm3 = wm2; wm2 = wm1; wm1 = cur;
        }
    }
}

extern "C" void kernel_launch(void* const* d_in, const int* in_sizes, int n_in,
                              void* d_out, int out_size, void* d_ws, size_t ws_size,
                              hipStream_t stream)
{
    (void)in_sizes; (void)n_in; (void)out_size; (void)d_ws; (void)ws_size;
    constexpr int B = 8, T = 4096, C = 1024;

    const float4* x = (const float4*)d_in[0];
    const float4* w = (const float4*)d_in[1];
    float4*       y = (float4*)d_out;

    dim3 block(C / 4);                        // 256 threads = 4 waves
    dim3 grid(B * (T / T_SPAN));              // 8 * 64 = 512 blocks

    DepthwiseCausalConv1d_57870389346354_kernel<<<grid, block, 0, stream>>>(
        x, w, y, T, C / 4);
}